// Round 2
// baseline (106.383 us; speedup 1.0000x reference)
//
#include <hip/hip_runtime.h>

typedef __bf16 bf16;
typedef __attribute__((ext_vector_type(8))) __bf16 bf16x8;
typedef __attribute__((ext_vector_type(4))) __bf16 bf16x4;
typedef __attribute__((ext_vector_type(2))) __bf16 bf16x2;
typedef __attribute__((ext_vector_type(4))) float floatx4;

#define MFMA16(a,b,c) __builtin_amdgcn_mfma_f32_16x16x32_bf16((a),(b),(c),0,0,0)

__device__ __forceinline__ float fast_exp2(float xv) {
#if __has_builtin(__builtin_amdgcn_exp2f)
  return __builtin_amdgcn_exp2f(xv);
#else
  return exp2f(xv);
#endif
}

__device__ __forceinline__ void ld8f(const bf16* p, float* dst) {
  bf16x8 v = *(const bf16x8*)p;
#pragma unroll
  for (int i = 0; i < 8; ++i) dst[i] = (float)v[i];
}

// Fused attention (heads 0-3) + depthwise-conv residual (heads 4-7).
// grid = 512 (b=128 x slice h), block = 512 (8 waves; wave w owns i-rows 32w..32w+31).
// R7: bank-conflict fix on the A-operand (aj) reads. Abf stride 36 dw == 4 (mod 32)
// puts row rho at bank-quad (rho+q) mod 8; old jp had jp%8 in {0..3} -> 16-way
// conflict. New jp = 8u+(c&3)+4*(u&1) is uniform mod 8 -> 8 lanes/quad (optimal).
// Induced output permutation pi(j) = j ^ ((j&8)>>1) (involution) is absorbed by
// storing ckA and VtF columns pi-permuted; math bitwise-identical to R6.
// smem: Abf[256][72] bf16 @0 (36864) | VtF[64][264] bf16 @36864 (33792; scT/bsT union
//       during init) | ckA f32 @70656 | cvA f32 @71680 | total 72704 -> 2 blk/CU.
__global__ __launch_bounds__(512, 4) void fused_kernel(
    const float* __restrict__ x,
    const float* __restrict__ bn_gamma, const float* __restrict__ bn_beta,
    const float* __restrict__ bn_mean, const float* __restrict__ bn_var,
    const float* __restrict__ w_qkv, const float* __restrict__ w_qs,
    const float* __restrict__ w_ks,
    float* __restrict__ out)
{
  __shared__ __align__(16) char smem[72704];
  bf16 (*Abf)[72]  = (bf16(*)[72])smem;
  bf16 (*VtF)[264] = (bf16(*)[264])(smem + 36864);
  float* ckA = (float*)(smem + 70656);
  float* cvA = (float*)(smem + 71680);
  float* scT = (float*)(smem + 36864);          // init-phase union with VtF
  float* bsT = (float*)(smem + 36864 + 1024);

  const int t  = threadIdx.x;
  const int bb = blockIdx.x >> 2;
  const int h  = blockIdx.x & 3;

  if (t < 256) {
    float inv = rsqrtf(bn_var[t] + 1e-5f);
    float sc  = bn_gamma[t] * inv;
    scT[t] = sc;
    bsT[t] = bn_beta[t] - bn_mean[t] * sc;
    // ckA stored pi-permuted: ckA[l] = ck[pi(l)], pi(l) = l ^ ((l&8)>>1) per 32-block
    int tp = t ^ ((t & 8) >> 1);
    ckA[t] = w_qkv[tp*6+2];
    cvA[t] = w_qkv[t*6+4];
  }
  __syncthreads();

  // stage A = relu(BN(x))[:, h*64 .. h*64+63] as bf16
  const float* xb = x + (size_t)bb * 65536 + h * 64;
  {
    const int rsub = t >> 4, ch = t & 15;
#pragma unroll
    for (int i2 = 0; i2 < 8; ++i2) {
      int n = i2*32 + rsub;
      float4 v = *(const float4*)(xb + (size_t)n*256 + ch*4);
      float sc = scT[n], bs = bsT[n];
      bf16x4 bv;
      bv.x = (bf16)fmaxf(fmaf(v.x, sc, bs), 0.f);
      bv.y = (bf16)fmaxf(fmaf(v.y, sc, bs), 0.f);
      bv.z = (bf16)fmaxf(fmaf(v.z, sc, bs), 0.f);
      bv.w = (bf16)fmaxf(fmaf(v.w, sc, bs), 0.f);
      *(bf16x4*)&Abf[n][ch*4] = bv;
    }
  }
  __syncthreads();   // Abf complete; scT/bsT dead -> VtF region reusable

  // build full V^T with cv folded, pi-permuted columns: VtF[e][l] = cv[pi(l)]*A[pi(l)][e].
  // Column pair (2J,2J+1) sources physical rows (2J_src, 2J_src+1), J_src = J^((J&4)>>1).
  {
    const int J  = t & 127;      // j-pair (column) index: cols 2J, 2J+1
    const int eg = t >> 7;       // e-group: e in [16eg, 16eg+16)
    const int Js = J ^ ((J & 4) >> 1);   // source row pair (pi involution)
    const bf16* r0 = &Abf[2*Js][16*eg];
    const bf16* r1 = &Abf[2*Js + 1][16*eg];
    bf16x8 a0l = *(const bf16x8*)r0, a0h = *(const bf16x8*)(r0 + 8);
    bf16x8 a1l = *(const bf16x8*)r1, a1h = *(const bf16x8*)(r1 + 8);
    float cv0 = cvA[2*Js], cv1 = cvA[2*Js + 1];
#pragma unroll
    for (int e = 0; e < 8; ++e) {
      union { bf16x2 hh; unsigned u; } wl, wh;
      wl.hh = (bf16x2){(bf16)((float)a0l[e]*cv0), (bf16)((float)a1l[e]*cv1)};
      wh.hh = (bf16x2){(bf16)((float)a0h[e]*cv0), (bf16)((float)a1h[e]*cv1)};
      *(unsigned*)&VtF[16*eg + e][2*J]     = wl.u;
      *(unsigned*)&VtF[16*eg + 8 + e][2*J] = wh.u;
    }
  }
  __syncthreads();   // VtF + Abf stable for the rest of the kernel

  const int lane = t & 63;
  const int wid  = t >> 6;
  const int q    = lane >> 4;
  const int c    = lane & 15;
  const int R    = wid * 32;
  // bank-uniform permuted j-row offset: f(c) = 8u + (c&3) + 4*(u&1); partner = f^4
  const int u    = c >> 2;
  const int jp   = (u << 3) + (c & 3) + ((u & 1) << 2);

  // B-operand (i-row) fragments, pre-scaled by cq_i * SCALE * log2(e)
  float cqs[2];
  cqs[0] = w_qkv[(R + c)*6]      * 0.18033688f;
  cqs[1] = w_qkv[(R + 16 + c)*6] * 0.18033688f;
  bf16x8 bi0[2], bi1[2];
#pragma unroll
  for (int it = 0; it < 2; ++it) {
    const bf16* bp = &Abf[R + 16*it + c][0];
    bf16x8 r0 = *(const bf16x8*)(bp + 8*q);
    bf16x8 r1 = *(const bf16x8*)(bp + 32 + 8*q);
#pragma unroll
    for (int e = 0; e < 8; ++e) {
      bi0[it][e] = (bf16)((float)r0[e] * cqs[it]);
      bi1[it][e] = (bf16)((float)r1[e] * cqs[it]);
    }
  }

  bf16x8 vbONE;
#pragma unroll
  for (int e = 0; e < 8; ++e) vbONE[e] = (bf16)1.0f;

  floatx4 oacc[2][4];
  floatx4 oaccL[2];
#pragma unroll
  for (int it = 0; it < 2; ++it) {
    oaccL[it] = (floatx4){0.f,0.f,0.f,0.f};
#pragma unroll
    for (int et = 0; et < 4; ++et)
      oacc[it][et] = (floatx4){0.f,0.f,0.f,0.f};
  }

  const int jbase = wid & 7;   // wave-staggered jt ring
#pragma unroll 2
  for (int jt = 0; jt < 8; ++jt) {
    const int j0 = (((jt + jbase) & 7) << 5);

    // issue this jt's V^T reads first: latency hides under S+exp below
    bf16x8 vb0 = *(const bf16x8*)&VtF[     c][j0 + 8*q];
    bf16x8 vb1 = *(const bf16x8*)&VtF[16 + c][j0 + 8*q];
    bf16x8 vb2 = *(const bf16x8*)&VtF[32 + c][j0 + 8*q];
    bf16x8 vb3 = *(const bf16x8*)&VtF[48 + c][j0 + 8*q];

    // A-operand = permuted j-rows (swapped-operand symmetric trick)
    const int jr = j0 + jp;
    bf16x8 aj00 = *(const bf16x8*)&Abf[jr][8*q];
    bf16x8 aj01 = *(const bf16x8*)&Abf[jr][32 + 8*q];
    bf16x8 aj10 = *(const bf16x8*)&Abf[jr ^ 4][8*q];
    bf16x8 aj11 = *(const bf16x8*)&Abf[jr ^ 4][32 + 8*q];
    floatx4 ck0 = *(const floatx4*)&ckA[j0 + 8*q];      // = ck[pi(8q+r)]
    floatx4 ck1 = *(const floatx4*)&ckA[j0 + 8*q + 4];  // = ck[pi(8q+4+r)]

    bf16x8 pa[2];
#pragma unroll
    for (int it = 0; it < 2; ++it) {
      floatx4 s0 = (floatx4){0.f,0.f,0.f,0.f};
      floatx4 s1 = (floatx4){0.f,0.f,0.f,0.f};
      s0 = MFMA16(aj00, bi0[it], s0); s0 = MFMA16(aj01, bi1[it], s0);
      s1 = MFMA16(aj10, bi0[it], s1); s1 = MFMA16(aj11, bi1[it], s1);
      // s pre-scaled by cq*SCALE*log2e; reg r: s0 -> j=j0+pi(8q+r), s1 -> j=j0+pi(8q+4+r)
      bf16x8 pv;
#pragma unroll
      for (int r = 0; r < 4; ++r) {
        pv[r]     = (bf16)fast_exp2(ck0[r] * s0[r]);
        pv[4 + r] = (bf16)fast_exp2(ck1[r] * s1[r]);
      }
      pa[it] = pv;
    }

    // rowsum via ones-MFMA: lands as l[R+16it+4q+r] in reg r (all c equal)
    oaccL[0] = MFMA16(pa[0], vbONE, oaccL[0]);
    oaccL[1] = MFMA16(pa[1], vbONE, oaccL[1]);

    oacc[0][0] = MFMA16(pa[0], vb0, oacc[0][0]);
    oacc[1][0] = MFMA16(pa[1], vb0, oacc[1][0]);
    oacc[0][1] = MFMA16(pa[0], vb1, oacc[0][1]);
    oacc[1][1] = MFMA16(pa[1], vb1, oacc[1][1]);
    oacc[0][2] = MFMA16(pa[0], vb2, oacc[0][2]);
    oacc[1][2] = MFMA16(pa[1], vb2, oacc[1][2]);
    oacc[0][3] = MFMA16(pa[0], vb3, oacc[0][3]);
    oacc[1][3] = MFMA16(pa[1], vb3, oacc[1][3]);
  }

  float* outA = out + ((size_t)bb*256)*256 + h*32;
#pragma unroll
  for (int it = 0; it < 2; ++it) {
#pragma unroll
    for (int r = 0; r < 4; ++r) {
      float linv = 0.5f / oaccL[it][r];            // fold pair-average 0.5
      int n = R + 16*it + 4*q + r;
#pragma unroll
      for (int et = 0; et < 4; ++et) {
        float v = oacc[it][et][r];
        float v2 = v + __shfl_xor(v, 1, 64);
        if (!(lane & 1))
          outA[(size_t)n*256 + 8*et + (c>>1)] = v2 * linv;
      }
    }
  }

  // ---------------- conv phase (heads 4..7), reads Abf ----------------
  // thread: C-row ci, quarter qq, half uh; p = 64*qq + 32*uh + k, k=0..31
  {
    const int ci = t >> 3, sub = t & 7, qq = sub >> 1, uh = sub & 1;
    const int C  = h*64 + ci;
    const int a  = 4*ci + qq;
    const int e0 = 32*uh;

    float qs0 = w_qs[C*3+0], qs1 = w_qs[C*3+1], qs2 = w_qs[C*3+2];
    float ks0 = w_ks[C*3+0], ks1 = w_ks[C*3+1], ks2 = w_ks[C*3+2];
    float wq1a = w_qkv[a*6+1], wk1a = w_qkv[a*6+3], wv1a = w_qkv[a*6+5];
    float wcf = fmaf(ks1, wk1a, wv1a);

    float wmx = 0.f;
    if (uh) wmx = ks0 * wk1a;
    else if (qq > 0) wmx = ks0 * w_qkv[(a-1)*6+3];
    float wmh = ks0 * wk1a;
    float wpl = ks2 * wk1a;
    float wpx = 0.f;
    if (!uh) wpx = ks2 * wk1a;
    else if (qq < 3) wpx = ks2 * w_qkv[(a+1)*6+3];

    float Xc[32], Xl[16], Xr[16];
#pragma unroll
    for (int m = 0; m < 4; ++m) ld8f(&Abf[a][e0 + 8*m], &Xc[8*m]);
    if (uh) {
      ld8f(&Abf[a][16], &Xl[0]); ld8f(&Abf[a][24], &Xl[8]);
    } else if (qq > 0) {
      ld8f(&Abf[a-1][48], &Xl[0]); ld8f(&Abf[a-1][56], &Xl[8]);
    } else {
#pragma unroll
      for (int i = 0; i < 16; ++i) Xl[i] = 0.f;
    }
    if (!uh) {
      ld8f(&Abf[a][32], &Xr[0]); ld8f(&Abf[a][40], &Xr[8]);
    } else if (qq < 3) {
      ld8f(&Abf[a+1][0], &Xr[0]); ld8f(&Abf[a+1][8], &Xr[8]);
    } else {
#pragma unroll
      for (int i = 0; i < 16; ++i) Xr[i] = 0.f;
    }

    float res[16];
    float prev = 0.f;
#pragma unroll
    for (int k = 0; k < 32; ++k) {
      float fc = Xc[k];
      float qv = qs1 * fc;
      if (k & 15)         qv = fmaf(qs0, Xc[k-1], qv);
      if ((k & 15) != 15) qv = fmaf(qs2, Xc[k+1], qv);
      float acc = fmaf(wq1a, qv, wcf * fc);
      float tm = (k < 16) ? Xl[k]     : Xc[k-16];
      float wm = (k < 16) ? wmx       : wmh;
      acc = fmaf(wm, tm, acc);
      float tp = (k < 16) ? Xc[k+16]  : Xr[k-16];
      float wp = (k < 16) ? wpl       : wpx;
      acc = fmaf(wp, tp, acc);
      if (k & 1) res[k>>1] = 0.5f * (prev + acc);
      else       prev = acc;
    }

    float* outC = out + ((size_t)(bb*256 + C))*256 + 128 + 32*qq + 16*uh;
#pragma unroll
    for (int m = 0; m < 4; ++m) {
      float4 o4;
      o4.x = res[4*m]; o4.y = res[4*m+1]; o4.z = res[4*m+2]; o4.w = res[4*m+3];
      *(float4*)(outC + 4*m) = o4;
    }
  }
}

extern "C" void kernel_launch(void* const* d_in, const int* in_sizes, int n_in,
                              void* d_out, int out_size, void* d_ws, size_t ws_size,
                              hipStream_t stream) {
  (void)in_sizes; (void)n_in; (void)out_size; (void)d_ws; (void)ws_size;
  const float* x    = (const float*)d_in[0];
  const float* g    = (const float*)d_in[1];
  const float* be   = (const float*)d_in[2];
  const float* mn   = (const float*)d_in[3];
  const float* vr   = (const float*)d_in[4];
  const float* wqkv = (const float*)d_in[5];
  const float* wqs  = (const float*)d_in[6];
  const float* wks  = (const float*)d_in[7];
  float* out = (float*)d_out;

  fused_kernel<<<dim3(512), dim3(512), 0, stream>>>(x, g, be, mn, vr, wqkv, wqs, wks, out);
}

// Round 4
// 105.039 us; speedup vs baseline: 1.0128x; 1.0128x over previous
//
#include <hip/hip_runtime.h>

typedef __bf16 bf16;
typedef __attribute__((ext_vector_type(8))) __bf16 bf16x8;
typedef __attribute__((ext_vector_type(4))) __bf16 bf16x4;
typedef __attribute__((ext_vector_type(2))) __bf16 bf16x2;
typedef __attribute__((ext_vector_type(4))) float floatx4;

#define MFMA16(a,b,c) __builtin_amdgcn_mfma_f32_16x16x32_bf16((a),(b),(c),0,0,0)

__device__ __forceinline__ float fast_exp2(float xv) {
#if __has_builtin(__builtin_amdgcn_exp2f)
  return __builtin_amdgcn_exp2f(xv);
#else
  return exp2f(xv);
#endif
}

__device__ __forceinline__ void ld8f(const bf16* p, float* dst) {
  bf16x8 v = *(const bf16x8*)p;
#pragma unroll
  for (int i = 0; i < 8; ++i) dst[i] = (float)v[i];
}

// Fused attention (heads 0-3) + depthwise-conv residual (heads 4-7).
// grid = 512 (b=128 x slice h), block = 512 (8 waves; wave w owns i-rows 32w..32w+31).
// R8: wave-local pipeline. Wave w stages rows [32w,32w+32) of Abf, then (after a
// wave-local lgkmcnt drain, NO barrier) builds its own VtF columns [32w,32w+32) and
// its own bi fragments. VtF/bi work of fast waves overlaps HBM streaming of slow
// waves; 3 barriers -> 2; the VtF transpose pass leaves the serial critical path.
// scT/bsT get a dedicated region (previously unioned with VtF - would now race).
// Values bitwise-identical to R7 (same ops, different writer assignment).
// Keeps R7's bank-uniform jp + pi(j)=j^((j&8)>>1) permutation (ckA/VtF pi-stored).
// smem: Abf[256][72] bf16 @0 (36864) | VtF[64][264] bf16 @36864 (33792) |
//       ckA f32 @70656 | cvA f32 @71680 | scT @72704 | bsT @73728 | total 74752
//       -> 2 blk/CU.
__global__ __launch_bounds__(512, 4) void fused_kernel(
    const float* __restrict__ x,
    const float* __restrict__ bn_gamma, const float* __restrict__ bn_beta,
    const float* __restrict__ bn_mean, const float* __restrict__ bn_var,
    const float* __restrict__ w_qkv, const float* __restrict__ w_qs,
    const float* __restrict__ w_ks,
    float* __restrict__ out)
{
  __shared__ __align__(16) char smem[74752];
  bf16 (*Abf)[72]  = (bf16(*)[72])smem;
  bf16 (*VtF)[264] = (bf16(*)[264])(smem + 36864);
  float* ckA = (float*)(smem + 70656);
  float* cvA = (float*)(smem + 71680);
  float* scT = (float*)(smem + 72704);
  float* bsT = (float*)(smem + 73728);

  const int t  = threadIdx.x;
  const int bb = blockIdx.x >> 2;
  const int h  = blockIdx.x & 3;

  const int lane = t & 63;
  const int wid  = t >> 6;

  if (t < 256) {
    float inv = rsqrtf(bn_var[t] + 1e-5f);
    float sc  = bn_gamma[t] * inv;
    scT[t] = sc;
    bsT[t] = bn_beta[t] - bn_mean[t] * sc;
    // ckA stored pi-permuted: ckA[l] = ck[pi(l)], pi(l) = l ^ ((l&8)>>1) per 32-block
    int tp = t ^ ((t & 8) >> 1);
    ckA[t] = w_qkv[tp*6+2];
    cvA[t] = w_qkv[t*6+4];
  }
  __syncthreads();   // scT/bsT/ckA/cvA visible to all

  // stage A = relu(BN(x))[:, h*64 .. h*64+63] as bf16 -- WAVE-LOCAL rows [32w,32w+32)
  const float* xb = x + (size_t)bb * 65536 + h * 64;
  {
    const int rsub = lane >> 4, ch = lane & 15;
#pragma unroll
    for (int i2 = 0; i2 < 8; ++i2) {
      int n = 32*wid + 4*i2 + rsub;
      float4 v = *(const float4*)(xb + (size_t)n*256 + ch*4);
      float sc = scT[n], bs = bsT[n];
      bf16x4 bv;
      bv.x = (bf16)fmaxf(fmaf(v.x, sc, bs), 0.f);
      bv.y = (bf16)fmaxf(fmaf(v.y, sc, bs), 0.f);
      bv.z = (bf16)fmaxf(fmaf(v.z, sc, bs), 0.f);
      bv.w = (bf16)fmaxf(fmaf(v.w, sc, bs), 0.f);
      *(bf16x4*)&Abf[n][ch*4] = bv;
    }
  }
  // wave-local drain: this wave's Abf rows are now readable by this wave (no barrier)
  asm volatile("s_waitcnt lgkmcnt(0)" ::: "memory");

  // build V^T columns for OWN rows, cv folded, pi-permuted columns:
  // VtF[e][l] = cv[pi(l)]*A[pi(l)][e]. Lane mapping: J = 16*wid + (lane&15),
  // eg = lane>>4; column pair (2J,2J+1) sources rows (2Js,2Js+1), Js = J^((J&4)>>1)
  // (pi keeps Js within the wave's 16 J-pairs -> wave-local reads).
  {
    const int J  = 16*wid + (lane & 15);
    const int eg = lane >> 4;
    const int Js = J ^ ((J & 4) >> 1);
    const bf16* r0 = &Abf[2*Js][16*eg];
    const bf16* r1 = &Abf[2*Js + 1][16*eg];
    bf16x8 a0l = *(const bf16x8*)r0, a0h = *(const bf16x8*)(r0 + 8);
    bf16x8 a1l = *(const bf16x8*)r1, a1h = *(const bf16x8*)(r1 + 8);
    float cv0 = cvA[2*Js], cv1 = cvA[2*Js + 1];
#pragma unroll
    for (int e = 0; e < 8; ++e) {
      union { bf16x2 hh; unsigned u; } wl, wh;
      wl.hh = (bf16x2){(bf16)((float)a0l[e]*cv0), (bf16)((float)a1l[e]*cv1)};
      wh.hh = (bf16x2){(bf16)((float)a0h[e]*cv0), (bf16)((float)a1h[e]*cv1)};
      *(unsigned*)&VtF[16*eg + e][2*J]     = wl.u;
      *(unsigned*)&VtF[16*eg + 8 + e][2*J] = wh.u;
    }
  }

  const int q    = lane >> 4;
  const int c    = lane & 15;
  const int R    = wid * 32;
  // bank-uniform permuted j-row offset: f(c) = 8u + (c&3) + 4*(u&1); partner = f^4
  const int u    = c >> 2;
  const int jp   = (u << 3) + (c & 3) + ((u & 1) << 2);

  // B-operand (i-row) fragments, pre-scaled by cq_i * SCALE * log2(e).
  // Reads only this wave's own rows [32w,32w+32) -> safe before the barrier.
  float cqs[2];
  cqs[0] = w_qkv[(R + c)*6]      * 0.18033688f;
  cqs[1] = w_qkv[(R + 16 + c)*6] * 0.18033688f;
  bf16x8 bi0[2], bi1[2];
#pragma unroll
  for (int it = 0; it < 2; ++it) {
    const bf16* bp = &Abf[R + 16*it + c][0];
    bf16x8 r0 = *(const bf16x8*)(bp + 8*q);
    bf16x8 r1 = *(const bf16x8*)(bp + 32 + 8*q);
#pragma unroll
    for (int e = 0; e < 8; ++e) {
      bi0[it][e] = (bf16)((float)r0[e] * cqs[it]);
      bi1[it][e] = (bf16)((float)r1[e] * cqs[it]);
    }
  }

  __syncthreads();   // all Abf + VtF ready for cross-wave reads

  bf16x8 vbONE;
#pragma unroll
  for (int e = 0; e < 8; ++e) vbONE[e] = (bf16)1.0f;

  floatx4 oacc[2][4];
  floatx4 oaccL[2];
#pragma unroll
  for (int it = 0; it < 2; ++it) {
    oaccL[it] = (floatx4){0.f,0.f,0.f,0.f};
#pragma unroll
    for (int et = 0; et < 4; ++et)
      oacc[it][et] = (floatx4){0.f,0.f,0.f,0.f};
  }

  const int jbase = wid & 7;   // wave-staggered jt ring
#pragma unroll 2
  for (int jt = 0; jt < 8; ++jt) {
    const int j0 = (((jt + jbase) & 7) << 5);

    // issue this jt's V^T reads first: latency hides under S+exp below
    bf16x8 vb0 = *(const bf16x8*)&VtF[     c][j0 + 8*q];
    bf16x8 vb1 = *(const bf16x8*)&VtF[16 + c][j0 + 8*q];
    bf16x8 vb2 = *(const bf16x8*)&VtF[32 + c][j0 + 8*q];
    bf16x8 vb3 = *(const bf16x8*)&VtF[48 + c][j0 + 8*q];

    // A-operand = permuted j-rows (swapped-operand symmetric trick)
    const int jr = j0 + jp;
    bf16x8 aj00 = *(const bf16x8*)&Abf[jr][8*q];
    bf16x8 aj01 = *(const bf16x8*)&Abf[jr][32 + 8*q];
    bf16x8 aj10 = *(const bf16x8*)&Abf[jr ^ 4][8*q];
    bf16x8 aj11 = *(const bf16x8*)&Abf[jr ^ 4][32 + 8*q];
    floatx4 ck0 = *(const floatx4*)&ckA[j0 + 8*q];      // = ck[pi(8q+r)]
    floatx4 ck1 = *(const floatx4*)&ckA[j0 + 8*q + 4];  // = ck[pi(8q+4+r)]

    bf16x8 pa[2];
#pragma unroll
    for (int it = 0; it < 2; ++it) {
      floatx4 s0 = (floatx4){0.f,0.f,0.f,0.f};
      floatx4 s1 = (floatx4){0.f,0.f,0.f,0.f};
      s0 = MFMA16(aj00, bi0[it], s0); s0 = MFMA16(aj01, bi1[it], s0);
      s1 = MFMA16(aj10, bi0[it], s1); s1 = MFMA16(aj11, bi1[it], s1);
      // s pre-scaled by cq*SCALE*log2e; reg r: s0 -> j=j0+pi(8q+r), s1 -> j=j0+pi(8q+4+r)
      bf16x8 pv;
#pragma unroll
      for (int r = 0; r < 4; ++r) {
        pv[r]     = (bf16)fast_exp2(ck0[r] * s0[r]);
        pv[4 + r] = (bf16)fast_exp2(ck1[r] * s1[r]);
      }
      pa[it] = pv;
    }

    // rowsum via ones-MFMA: lands as l[R+16it+4q+r] in reg r (all c equal)
    oaccL[0] = MFMA16(pa[0], vbONE, oaccL[0]);
    oaccL[1] = MFMA16(pa[1], vbONE, oaccL[1]);

    oacc[0][0] = MFMA16(pa[0], vb0, oacc[0][0]);
    oacc[1][0] = MFMA16(pa[1], vb0, oacc[1][0]);
    oacc[0][1] = MFMA16(pa[0], vb1, oacc[0][1]);
    oacc[1][1] = MFMA16(pa[1], vb1, oacc[1][1]);
    oacc[0][2] = MFMA16(pa[0], vb2, oacc[0][2]);
    oacc[1][2] = MFMA16(pa[1], vb2, oacc[1][2]);
    oacc[0][3] = MFMA16(pa[0], vb3, oacc[0][3]);
    oacc[1][3] = MFMA16(pa[1], vb3, oacc[1][3]);
  }

  float* outA = out + ((size_t)bb*256)*256 + h*32;
#pragma unroll
  for (int it = 0; it < 2; ++it) {
#pragma unroll
    for (int r = 0; r < 4; ++r) {
      float linv = 0.5f / oaccL[it][r];            // fold pair-average 0.5
      int n = R + 16*it + 4*q + r;
#pragma unroll
      for (int et = 0; et < 4; ++et) {
        float v = oacc[it][et][r];
        float v2 = v + __shfl_xor(v, 1, 64);
        if (!(lane & 1))
          outA[(size_t)n*256 + 8*et + (c>>1)] = v2 * linv;
      }
    }
  }

  // ---------------- conv phase (heads 4..7), reads Abf ----------------
  // thread: C-row ci, quarter qq, half uh; p = 64*qq + 32*uh + k, k=0..31
  {
    const int ci = t >> 3, sub = t & 7, qq = sub >> 1, uh = sub & 1;
    const int C  = h*64 + ci;
    const int a  = 4*ci + qq;
    const int e0 = 32*uh;

    float qs0 = w_qs[C*3+0], qs1 = w_qs[C*3+1], qs2 = w_qs[C*3+2];
    float ks0 = w_ks[C*3+0], ks1 = w_ks[C*3+1], ks2 = w_ks[C*3+2];
    float wq1a = w_qkv[a*6+1], wk1a = w_qkv[a*6+3], wv1a = w_qkv[a*6+5];
    float wcf = fmaf(ks1, wk1a, wv1a);

    float wmx = 0.f;
    if (uh) wmx = ks0 * wk1a;
    else if (qq > 0) wmx = ks0 * w_qkv[(a-1)*6+3];
    float wmh = ks0 * wk1a;
    float wpl = ks2 * wk1a;
    float wpx = 0.f;
    if (!uh) wpx = ks2 * wk1a;
    else if (qq < 3) wpx = ks2 * w_qkv[(a+1)*6+3];

    float Xc[32], Xl[16], Xr[16];
#pragma unroll
    for (int m = 0; m < 4; ++m) ld8f(&Abf[a][e0 + 8*m], &Xc[8*m]);
    if (uh) {
      ld8f(&Abf[a][16], &Xl[0]); ld8f(&Abf[a][24], &Xl[8]);
    } else if (qq > 0) {
      ld8f(&Abf[a-1][48], &Xl[0]); ld8f(&Abf[a-1][56], &Xl[8]);
    } else {
#pragma unroll
      for (int i = 0; i < 16; ++i) Xl[i] = 0.f;
    }
    if (!uh) {
      ld8f(&Abf[a][32], &Xr[0]); ld8f(&Abf[a][40], &Xr[8]);
    } else if (qq < 3) {
      ld8f(&Abf[a+1][0], &Xr[0]); ld8f(&Abf[a+1][8], &Xr[8]);
    } else {
#pragma unroll
      for (int i = 0; i < 16; ++i) Xr[i] = 0.f;
    }

    float res[16];
    float prev = 0.f;
#pragma unroll
    for (int k = 0; k < 32; ++k) {
      float fc = Xc[k];
      float qv = qs1 * fc;
      if (k & 15)         qv = fmaf(qs0, Xc[k-1], qv);
      if ((k & 15) != 15) qv = fmaf(qs2, Xc[k+1], qv);
      float acc = fmaf(wq1a, qv, wcf * fc);
      float tm = (k < 16) ? Xl[k]     : Xc[k-16];
      float wm = (k < 16) ? wmx       : wmh;
      acc = fmaf(wm, tm, acc);
      float tp = (k < 16) ? Xc[k+16]  : Xr[k-16];
      float wp = (k < 16) ? wpl       : wpx;
      acc = fmaf(wp, tp, acc);
      if (k & 1) res[k>>1] = 0.5f * (prev + acc);
      else       prev = acc;
    }

    float* outC = out + ((size_t)(bb*256 + C))*256 + 128 + 32*qq + 16*uh;
#pragma unroll
    for (int m = 0; m < 4; ++m) {
      float4 o4;
      o4.x = res[4*m]; o4.y = res[4*m+1]; o4.z = res[4*m+2]; o4.w = res[4*m+3];
      *(float4*)(outC + 4*m) = o4;
    }
  }
}

extern "C" void kernel_launch(void* const* d_in, const int* in_sizes, int n_in,
                              void* d_out, int out_size, void* d_ws, size_t ws_size,
                              hipStream_t stream) {
  (void)in_sizes; (void)n_in; (void)out_size; (void)d_ws; (void)ws_size;
  const float* x    = (const float*)d_in[0];
  const float* g    = (const float*)d_in[1];
  const float* be   = (const float*)d_in[2];
  const float* mn   = (const float*)d_in[3];
  const float* vr   = (const float*)d_in[4];
  const float* wqkv = (const float*)d_in[5];
  const float* wqs  = (const float*)d_in[6];
  const float* wks  = (const float*)d_in[7];
  float* out = (float*)d_out;

  fused_kernel<<<dim3(512), dim3(512), 0, stream>>>(x, g, be, mn, vr, wqkv, wqs, wks, out);
}